// Round 6
// baseline (255.220 us; speedup 1.0000x reference)
//
#include <hip/hip_runtime.h>

#define D 256

typedef __attribute__((ext_vector_type(8))) short bf16x8;
typedef __attribute__((ext_vector_type(8))) unsigned short u16x8;
typedef __attribute__((ext_vector_type(4))) float f32x4;

__device__ __forceinline__ unsigned short bfr(float x) {
    unsigned u = __float_as_uint(x);
    unsigned r = (u + 0x7fffu + ((u >> 16) & 1u)) >> 16;
    return (unsigned short)r;
}
__device__ __forceinline__ float bf2f(unsigned short u) {
    return __uint_as_float(((unsigned)u) << 16);
}
__device__ __forceinline__ void gload_lds16(const void* g, void* l) {
    __builtin_amdgcn_global_load_lds((const __attribute__((address_space(1))) unsigned int*)g,
                                     (__attribute__((address_space(3))) unsigned int*)l, 16, 0, 0);
}

// ---------------- fp32->bf16 convert (h, W1, W2) + degree histogram ----------------
__global__ void cvt_hist_kernel(const float* __restrict__ in, unsigned short* __restrict__ out,
                                long n4, const int* __restrict__ dst, int* __restrict__ counts,
                                int E, const float* __restrict__ W1, const float* __restrict__ W2,
                                unsigned short* __restrict__ w1b, unsigned short* __restrict__ w2b) {
    long stride = (long)gridDim.x * blockDim.x;
    long i0 = (long)blockIdx.x * blockDim.x + threadIdx.x;
    for (long i = i0; i < n4; i += stride) {
        float4 v = reinterpret_cast<const float4*>(in)[i];
        ushort4 o;
        o.x = bfr(v.x); o.y = bfr(v.y); o.z = bfr(v.z); o.w = bfr(v.w);
        reinterpret_cast<ushort4*>(out)[i] = o;
    }
    for (long i = i0; i < E; i += stride) atomicAdd(&counts[dst[i]], 1);
    for (long i = i0; i < 16384; i += stride) {
        float4 a = reinterpret_cast<const float4*>(W1)[i];
        float4 b = reinterpret_cast<const float4*>(W2)[i];
        ushort4 oa, ob;
        oa.x = bfr(a.x); oa.y = bfr(a.y); oa.z = bfr(a.z); oa.w = bfr(a.w);
        ob.x = bfr(b.x); ob.y = bfr(b.y); ob.z = bfr(b.z); ob.w = bfr(b.w);
        reinterpret_cast<ushort4*>(w1b)[i] = oa;
        reinterpret_cast<ushort4*>(w2b)[i] = ob;
    }
}

// ---------------- CSR scan ----------------
__global__ void scan1_kernel(const int* __restrict__ counts, int* __restrict__ blocksums, int n) {
    int b = blockIdx.x, t = threadIdx.x;
    int base = b * 1024 + t * 4;
    int s = 0;
    if (base + 3 < n) {
        int4 c = *reinterpret_cast<const int4*>(&counts[base]);
        s = c.x + c.y + c.z + c.w;
    } else {
        for (int i = 0; i < 4; ++i) if (base + i < n) s += counts[base + i];
    }
    int lane = t & 63, w = t >> 6;
    for (int off = 1; off < 64; off <<= 1) s += __shfl_xor(s, off, 64);
    __shared__ int ws_[4];
    if (lane == 0) ws_[w] = s;
    __syncthreads();
    if (t == 0) blocksums[b] = ws_[0] + ws_[1] + ws_[2] + ws_[3];
}

__global__ void scan3_kernel(const int* __restrict__ counts, const int* __restrict__ blocksums,
                             int* __restrict__ offsets, int n, int nb) {
    __shared__ int bo_s;
    int b = blockIdx.x, t = threadIdx.x;
    if (t < 64) {
        int v = (t < nb) ? blocksums[t] : 0;
#pragma unroll
        for (int off = 1; off < 64; off <<= 1) {
            int u = __shfl_up(v, off, 64);
            if (t >= off) v += u;
        }
        int bo = (b == 0) ? 0 : __shfl(v, b - 1, 64);
        if (t == 0) bo_s = bo;
    }
    __syncthreads();
    int base = b * 1024 + t * 4;
    int c0 = 0, c1 = 0, c2 = 0, c3 = 0;
    if (base + 3 < n) {
        int4 c = *reinterpret_cast<const int4*>(&counts[base]);
        c0 = c.x; c1 = c.y; c2 = c.z; c3 = c.w;
    } else {
        if (base + 0 < n) c0 = counts[base + 0];
        if (base + 1 < n) c1 = counts[base + 1];
        if (base + 2 < n) c2 = counts[base + 2];
        if (base + 3 < n) c3 = counts[base + 3];
    }
    int s0 = c0, s1 = s0 + c1, s2 = s1 + c2, s3 = s2 + c3;
    int lane = t & 63, w = t >> 6;
    int v = s3;
    for (int off = 1; off < 64; off <<= 1) {
        int u = __shfl_up(v, off, 64);
        if (lane >= off) v += u;
    }
    __shared__ int wsum[4];
    if (lane == 63) wsum[w] = v;
    __syncthreads();
    int woff = 0;
#pragma unroll
    for (int i = 0; i < 4; ++i) if (i < w) woff += wsum[i];
    int p = bo_s + woff + (v - s3);
    if (base + 0 < n) offsets[base + 1] = p + s0;
    if (base + 1 < n) offsets[base + 2] = p + s1;
    if (base + 2 < n) offsets[base + 3] = p + s2;
    if (base + 3 < n) offsets[base + 4] = p + s3;
    if (b == 0 && t == 0) offsets[0] = 0;
}

__global__ void fill_kernel(const int* __restrict__ src, const float* __restrict__ e,
                            const int* __restrict__ dst, const int* __restrict__ offsets,
                            int* __restrict__ cursor, int2* __restrict__ ev, int E) {
    int i = blockIdx.x * blockDim.x + threadIdx.x;
    if (i < E) {
        int d = dst[i];
        int p = offsets[d] + atomicAdd(&cursor[d], 1);
        ev[p] = make_int2(src[i], __float_as_int(e[i]));
    }
}

// ---------------- aggregation: 2 nodes per wave (32 lanes each), 16B loads ----------------
__global__ void aggregate_kernel(const unsigned short* __restrict__ hb, const int2* __restrict__ ev,
                                 const int* __restrict__ offsets, unsigned short* __restrict__ hnb,
                                 int n_nodes) {
    int node = blockIdx.x * 8 + (threadIdx.x >> 5);
    if (node >= n_nodes) return;
    int sl = threadIdx.x & 31;
    int beg = offsets[node], end = offsets[node + 1];
    float acc[8] = {0.f, 0.f, 0.f, 0.f, 0.f, 0.f, 0.f, 0.f};
    int k = beg;
    for (; k + 4 <= end; k += 4) {
        int2 ee[4];
        u16x8 hh[4];
#pragma unroll
        for (int u = 0; u < 4; ++u) ee[u] = ev[k + u];
#pragma unroll
        for (int u = 0; u < 4; ++u)
            hh[u] = *reinterpret_cast<const u16x8*>(&hb[(size_t)ee[u].x * D + sl * 8]);
#pragma unroll
        for (int u = 0; u < 4; ++u) {
            float w0 = __int_as_float(ee[u].y);
#pragma unroll
            for (int j = 0; j < 8; ++j) acc[j] += bf2f(hh[u][j]) * w0;
        }
    }
    for (; k < end; ++k) {
        int2 e0 = ev[k];
        u16x8 h0 = *reinterpret_cast<const u16x8*>(&hb[(size_t)e0.x * D + sl * 8]);
        float w0 = __int_as_float(e0.y);
#pragma unroll
        for (int j = 0; j < 8; ++j) acc[j] += bf2f(h0[j]) * w0;
    }
    int deg = end - beg;
    float inv = (deg > 0) ? (1.0f / (float)deg) : 0.0f;
    u16x8 o;
#pragma unroll
    for (int j = 0; j < 8; ++j) o[j] = bfr(acc[j] * inv);
    *reinterpret_cast<u16x8*>(&hnb[(size_t)node * D + sl * 8]) = o;
}

// ---------------- bf16 MFMA GEMM: C[M,256] = relu(A[M,256] @ Wb[256,256]^T + bias) ----------------
// BM=64, BN=256 (full width), BK=64. 4 waves, each 64 rows x 64 cols.
// global_load_lds staging with pre-swizzled source; XOR-swizzled ds_read_b128.
// FUSE_STATS: per-block column sum/sumsq partials, partial[col][blk].
template <int FUSE_STATS>
__global__ __launch_bounds__(256) void gemm_kernel(const unsigned short* __restrict__ A,
                                                   const unsigned short* __restrict__ Wb,
                                                   const float* __restrict__ bias,
                                                   unsigned short* __restrict__ Cout,
                                                   float* __restrict__ partial, int P, int M) {
    __shared__ short As[64 * 64];    // 8KB  [r][k], 128B rows, swizzled
    __shared__ short Bs[256 * 64];   // 32KB [n][k], 128B rows, swizzled
    const int t = threadIdx.x;
    const int row0 = blockIdx.x * 64;
    const int lane = t & 63;
    const int w = t >> 6;
    const int lr = lane & 15;
    const int q = lane >> 4;
    const int swz = (lr & 7) << 4;

    f32x4 zero = {0.f, 0.f, 0.f, 0.f};
    f32x4 acc[4][4];
#pragma unroll
    for (int i = 0; i < 4; ++i)
#pragma unroll
        for (int j = 0; j < 4; ++j) acc[i][j] = zero;

#pragma unroll
    for (int kt = 0; kt < 4; ++kt) {
        // stage A tile: 64 rows x 128B
#pragma unroll
        for (int i = 0; i < 2; ++i) {
            int g = i * 256 + t;
            int r = g >> 3;
            int kb = ((g & 7) << 4) ^ ((r & 7) << 4);
            const char* srcp = reinterpret_cast<const char*>(A) + (size_t)(row0 + r) * 512 +
                               kt * 128 + kb;
            gload_lds16(srcp, reinterpret_cast<char*>(As) + g * 16);
        }
        // stage B tile: 256 rows x 128B
#pragma unroll
        for (int i = 0; i < 8; ++i) {
            int g = i * 256 + t;
            int r = g >> 3;
            int kb = ((g & 7) << 4) ^ ((r & 7) << 4);
            const char* srcp = reinterpret_cast<const char*>(Wb) + (size_t)r * 512 + kt * 128 + kb;
            gload_lds16(srcp, reinterpret_cast<char*>(Bs) + g * 16);
        }
        __syncthreads();
#pragma unroll
        for (int ks = 0; ks < 2; ++ks) {
            int kb = ks * 64 + q * 16;
            bf16x8 a[4], b[4];
#pragma unroll
            for (int fr = 0; fr < 4; ++fr)
                a[fr] = *reinterpret_cast<const bf16x8*>(reinterpret_cast<const char*>(As) +
                                                         (fr * 16 + lr) * 128 + (kb ^ swz));
#pragma unroll
            for (int fc = 0; fc < 4; ++fc)
                b[fc] = *reinterpret_cast<const bf16x8*>(reinterpret_cast<const char*>(Bs) +
                                                         (w * 64 + fc * 16 + lr) * 128 + (kb ^ swz));
#pragma unroll
            for (int fr = 0; fr < 4; ++fr)
#pragma unroll
                for (int fc = 0; fc < 4; ++fc)
                    acc[fr][fc] = __builtin_amdgcn_mfma_f32_16x16x32_bf16(a[fr], b[fc],
                                                                          acc[fr][fc], 0, 0, 0);
        }
        if (kt < 3) __syncthreads();
    }

    float csum[4] = {0.f, 0.f, 0.f, 0.f};
    float csq[4] = {0.f, 0.f, 0.f, 0.f};
#pragma unroll
    for (int fc = 0; fc < 4; ++fc) {
        int col = w * 64 + fc * 16 + lr;
        float bv = bias[col];
#pragma unroll
        for (int fr = 0; fr < 4; ++fr) {
#pragma unroll
            for (int rr = 0; rr < 4; ++rr) {
                int row = row0 + fr * 16 + q * 4 + rr;
                if (row < M) {
                    float v = fmaxf(acc[fr][fc][rr] + bv, 0.f);
                    Cout[(size_t)row * D + col] = bfr(v);
                    if (FUSE_STATS) { csum[fc] += v; csq[fc] += v * v; }
                }
            }
        }
    }

    if (FUSE_STATS) {
#pragma unroll
        for (int fc = 0; fc < 4; ++fc) {
            float s = csum[fc], qq = csq[fc];
            s += __shfl_xor(s, 16, 64); s += __shfl_xor(s, 32, 64);
            qq += __shfl_xor(qq, 16, 64); qq += __shfl_xor(qq, 32, 64);
            if (lane < 16) {
                int col = w * 64 + fc * 16 + lane;
                partial[(size_t)col * P + blockIdx.x] = s;
                partial[(size_t)(col + 256) * P + blockIdx.x] = qq;
            }
        }
    }
}

// one block per channel c; coalesced reads of partial[c][*]
__global__ void bn_finalize_kernel(const float* __restrict__ partial, const float* __restrict__ gamma,
                                   const float* __restrict__ beta, float* __restrict__ scaleshift,
                                   int nrb, int P, int n) {
    int c = blockIdx.x;
    int t = threadIdx.x;
    float s = 0.f, q = 0.f;
    for (int b = t; b < nrb; b += 256) {
        s += partial[(size_t)c * P + b];
        q += partial[(size_t)(c + 256) * P + b];
    }
    int lane = t & 63, w = t >> 6;
    for (int off = 1; off < 64; off <<= 1) {
        s += __shfl_xor(s, off, 64);
        q += __shfl_xor(q, off, 64);
    }
    __shared__ float ss[4], qs[4];
    if (lane == 0) { ss[w] = s; qs[w] = q; }
    __syncthreads();
    if (t == 0) {
        float S = ss[0] + ss[1] + ss[2] + ss[3];
        float Q = qs[0] + qs[1] + qs[2] + qs[3];
        float mu = S / (float)n;
        float var = Q / (float)n - mu * mu;
        float rs = rsqrtf(var + 1e-5f);
        float sc = gamma[c] * rs;
        scaleshift[c] = sc;
        scaleshift[D + c] = beta[c] - mu * sc;
    }
}

__global__ void bn_apply_kernel(float* __restrict__ out, const unsigned short* __restrict__ x2b,
                                const unsigned short* __restrict__ hnb,
                                const float* __restrict__ scaleshift, long total4) {
    long stride = (long)gridDim.x * blockDim.x;
    for (long i = (long)blockIdx.x * blockDim.x + threadIdx.x; i < total4; i += stride) {
        int c4 = (int)(i & 63);
        ushort4 xu = reinterpret_cast<const ushort4*>(x2b)[i];
        ushort4 hu = reinterpret_cast<const ushort4*>(hnb)[i];
        float4 sc = reinterpret_cast<const float4*>(scaleshift)[c4];
        float4 sh = reinterpret_cast<const float4*>(scaleshift)[64 + c4];
        float4 v;
        v.x = bf2f(xu.x) * sc.x + sh.x + bf2f(hu.x);
        v.y = bf2f(xu.y) * sc.y + sh.y + bf2f(hu.y);
        v.z = bf2f(xu.z) * sc.z + sh.z + bf2f(hu.z);
        v.w = bf2f(xu.w) * sc.w + sh.w + bf2f(hu.w);
        reinterpret_cast<float4*>(out)[i] = v;
    }
}

extern "C" void kernel_launch(void* const* d_in, const int* in_sizes, int n_in,
                              void* d_out, int out_size, void* d_ws, size_t ws_size,
                              hipStream_t stream) {
    const float* h     = (const float*)d_in[0];
    const float* e     = (const float*)d_in[1];
    const int*   src   = (const int*)d_in[2];
    const int*   dst   = (const int*)d_in[3];
    const float* W1    = (const float*)d_in[4];
    const float* b1    = (const float*)d_in[5];
    const float* W2    = (const float*)d_in[6];
    const float* b2    = (const float*)d_in[7];
    const float* gamma = (const float*)d_in[8];
    const float* beta  = (const float*)d_in[9];
    float* out = (float*)d_out;

    const int N = in_sizes[0] / D;
    const int E = in_sizes[2];
    const size_t NB = (size_t)N * D;
    const int nrb = (N + 63) / 64;
    const int P = (nrb + 15) & ~15;
    const int nb1 = (N + 1023) / 1024;

    char* ws = (char*)d_ws;
    unsigned short* h_bf = (unsigned short*)ws; ws += NB * 2;   // dead after aggregate
    unsigned short* hnb  = (unsigned short*)ws; ws += NB * 2;
    unsigned short* x1b  = (unsigned short*)ws; ws += NB * 2;
    int2* ev             = (int2*)ws;           ws += (size_t)E * 8;
    float* partial       = (float*)ws;          ws += (size_t)512 * P * 4;
    float* scaleshift    = (float*)ws;          ws += 2 * D * sizeof(float);
    int* offsets         = (int*)ws;            ws += (size_t)(N + 1) * 4;
    int* counts          = (int*)ws;            ws += (size_t)N * 4;
    int* cursor          = (int*)ws;            ws += (size_t)N * 4;
    int* blocksums       = (int*)ws;            ws += 64 * 4;
    unsigned short* w1b  = (unsigned short*)ws; ws += (size_t)D * D * 2;
    unsigned short* w2b  = (unsigned short*)ws; ws += (size_t)D * D * 2;
    unsigned short* x2b  = h_bf;                // alias: reuse h_bf region

    hipMemsetAsync(counts, 0, (size_t)2 * N * 4, stream);

    cvt_hist_kernel<<<2048, 256, 0, stream>>>(h, h_bf, (long)(NB / 4), dst, counts, E,
                                              W1, W2, w1b, w2b);
    scan1_kernel<<<nb1, 256, 0, stream>>>(counts, blocksums, N);
    scan3_kernel<<<nb1, 256, 0, stream>>>(counts, blocksums, offsets, N, nb1);
    fill_kernel<<<(E + 255) / 256, 256, 0, stream>>>(src, e, dst, offsets, cursor, ev, E);

    aggregate_kernel<<<(N + 7) / 8, 256, 0, stream>>>(h_bf, ev, offsets, hnb, N);

    gemm_kernel<0><<<nrb, 256, 0, stream>>>(hnb, w1b, b1, x1b, nullptr, P, N);
    gemm_kernel<1><<<nrb, 256, 0, stream>>>(x1b, w2b, b2, x2b, partial, P, N);

    bn_finalize_kernel<<<256, 256, 0, stream>>>(partial, gamma, beta, scaleshift, nrb, P, N);
    bn_apply_kernel<<<2048, 256, 0, stream>>>(out, x2b, hnb, scaleshift, (long)(NB / 4));
}